// Round 7
// baseline (135.870 us; speedup 1.0000x reference)
//
#include <hip/hip_runtime.h>
#include <hip/hip_bf16.h>
#include <math.h>

#define B_N 8192
#define E_N 512
#define T_N 32

typedef short bf16x8 __attribute__((ext_vector_type(8)));
typedef float f32x4 __attribute__((ext_vector_type(4)));

// ---------------- ws layout (bytes) ----------------
#define WS_OFFS   256      // fallback
#define WS_RANK   512      // fallback
#define WS_ORDER  33280    // fallback
#define WS_YACC   66048    // fallback
#define WS_YACC8  98816    // main: 8 x 8192 floats (256 KB), slab = nt*2 + (wave&1)
#define WS_W1T    360960   // main: bf16 W1 transposed [32][512(n)][512(k)] (16 MB)
#define WS_REQ    (WS_W1T + 16777216)

typedef __attribute__((address_space(1))) const unsigned int gas_u32;
typedef __attribute__((address_space(3))) unsigned int las_u32;

static __device__ __forceinline__ unsigned short f2bf(float f) {
    unsigned int u = __float_as_uint(f);
    unsigned int r = u + 0x7fffu + ((u >> 16) & 1u);  // RNE
    return (unsigned short)(r >> 16);
}

// packed f32x2 -> bf16x2 (RNE)
static __device__ __forceinline__ unsigned int pk2(float a, float b) {
    __hip_bfloat162 h = __float22bfloat162_rn(float2{a, b});
    unsigned int u;
    __builtin_memcpy(&u, &h, 4);
    return u;
}

// ---------- pre-pass: W1[t][k][n] fp32 -> W1T[t][n][k] bf16 (64x64 LDS transpose) ----------
__global__ __launch_bounds__(256) void k_pre(const float* __restrict__ W1,
                                             unsigned short* __restrict__ W1T) {
    __shared__ float T[64][65];
    int cid = blockIdx.x, tid = threadIdx.x;
    int t = cid >> 6, r = cid & 63;
    int k0 = (r >> 3) * 64, n0 = (r & 7) * 64;
    int g = tid >> 4, c = tid & 15;
#pragma unroll
    for (int p = 0; p < 4; ++p) {
        int row = p * 16 + g;  // k within tile
        float4 v = *(const float4*)(W1 + ((size_t)t * E_N + k0 + row) * E_N + n0 + c * 4);
        T[c * 4 + 0][row] = v.x;
        T[c * 4 + 1][row] = v.y;
        T[c * 4 + 2][row] = v.z;
        T[c * 4 + 3][row] = v.w;
    }
    __syncthreads();
#pragma unroll
    for (int p = 0; p < 4; ++p) {
        int n = p * 16 + g;
        ushort4 o;
        o.x = f2bf(T[n][c * 4 + 0]);
        o.y = f2bf(T[n][c * 4 + 1]);
        o.z = f2bf(T[n][c * 4 + 2]);
        o.w = f2bf(T[n][c * 4 + 3]);
        *(ushort4*)(W1T + ((size_t)t * E_N + n0 + n) * E_N + k0 + c * 4) = o;
    }
}

// ---------- MFMA GEMM v5.1: embedded sort-slice, dual DMA pipeline, 8-slab plain stores ----------
__global__ __launch_bounds__(256) void k_gemm_mfma(
    const float* __restrict__ g_exp, const unsigned short* __restrict__ W1T,
    const int* __restrict__ tv, const float* __restrict__ b1,
    const float* __restrict__ W2, float* __restrict__ yacc8) {
    int wi = blockIdx.x;
    int mt = wi >> 7;  // m-tile slowest: live blocks pack onto distinct CUs
    int rem = wi & 127;
    int t = rem >> 2, nt = rem & 3;
    int m0 = mt * 128, n0 = nt * 128;

    int tid = threadIdx.x;
    int wave = tid >> 6, lane = tid & 63;
    int quad = lane >> 4, l15 = lane & 15;
    int wm = (wave >> 1) * 64, wn = (wave & 1) * 64;

    __shared__ int wsum[4];
    __shared__ int rows_s[128];  // global b for sorted rows m0..m0+127

    // ---- embedded counting-sort slice: which b's are sorted rows [m0, m0+128) of tissue t ----
    int tvals[32];
    const int4* tvp = (const int4*)(tv + tid * 32);
#pragma unroll
    for (int j = 0; j < 8; ++j) ((int4*)tvals)[j] = tvp[j];
    int myc = 0;
#pragma unroll
    for (int j = 0; j < 32; ++j) myc += (tvals[j] == t) ? 1 : 0;
    int inc = myc;
#pragma unroll
    for (int o = 1; o < 64; o <<= 1) {
        int u = __shfl_up(inc, o, 64);
        if (lane >= o) inc += u;
    }
    if (lane == 63) wsum[wave] = inc;
    if (tid < 128) rows_s[tid] = 0;
    __syncthreads();
    int n_t = wsum[0] + wsum[1] + wsum[2] + wsum[3];
    if (m0 >= n_t) return;  // uniform across block
    int wbase = 0;
    for (int i = 0; i < wave; ++i) wbase += wsum[i];
    int rk = wbase + inc - myc;  // exclusive within-tissue rank at this thread's chunk start
#pragma unroll
    for (int j = 0; j < 32; ++j)
        if (tvals[j] == t) {
            int rr = rk++;
            if (rr >= m0 && rr < m0 + 128) rows_s[rr - m0] = tid * 32 + j;
        }
    __syncthreads();

    // ---- DMA source pointers ----
    // B tile: 128n x 32k bf16 = 512 chunks; chunk d: row=d>>2, kc=(d&3)^(row&3)
    const unsigned short* Bsrc = W1T + ((size_t)t * E_N + n0) * E_N;
    int bd0 = tid, bd1 = tid + 256;
    int brow0 = bd0 >> 2, bkc = (bd0 & 3) ^ (brow0 & 3);  // same kc for bd1 (row+64)
    const unsigned short* pB0 = Bsrc + (size_t)brow0 * E_N + bkc * 8;
    const unsigned short* pB1 = Bsrc + (size_t)(brow0 + 64) * E_N + bkc * 8;
    // A tile: 128m x 32k fp32 = 1024 chunks; chunk d: row=d>>3, kc=(d&7)^(row&7)
    const float* pA[4];
#pragma unroll
    for (int p = 0; p < 4; ++p) {
        int d = tid + 256 * p, arow = d >> 3, akc = (d & 7) ^ (arow & 7);
        pA[p] = g_exp + (size_t)rows_s[arow] * E_N + akc * 4;
    }

    __shared__ __align__(16) float As[3][128 * 32];            // 48 KB
    __shared__ __align__(16) unsigned short Bsh[3][128 * 32];  // 24 KB

    f32x4 acc[4][4];
#pragma unroll
    for (int mi = 0; mi < 4; ++mi)
#pragma unroll
        for (int ni = 0; ni < 4; ++ni) acc[mi][ni] = (f32x4){0.f, 0.f, 0.f, 0.f};

#define ISSUE(kk) do {                                                                         \
        int _ko = (kk) * 32;                                                                   \
        __builtin_amdgcn_global_load_lds((gas_u32*)(pB0 + _ko),                                \
                                         (las_u32*)&Bsh[(kk) % 3][bd0 * 8], 16, 0, 0);         \
        __builtin_amdgcn_global_load_lds((gas_u32*)(pB1 + _ko),                                \
                                         (las_u32*)&Bsh[(kk) % 3][bd1 * 8], 16, 0, 0);         \
        _Pragma("unroll") for (int p = 0; p < 4; ++p)                                          \
            __builtin_amdgcn_global_load_lds((gas_u32*)(pA[p] + _ko),                          \
                                             (las_u32*)&As[(kk) % 3][(tid + 256 * p) * 4],     \
                                             16, 0, 0);                                        \
    } while (0)

    ISSUE(0);
    ISSUE(1);

    // Stage it: vmcnt(6) leaves only tile it+1's 6 DMAs outstanding -> tile it landed.
    // Raw s_barrier (no compiler vmcnt(0) drain). Refill buffer (it+2)%3 = buffer read at
    // stage it-1, sealed by this stage's barrier.
#define STAGE(it, W) do {                                                                      \
        asm volatile("s_waitcnt vmcnt(%0)" :: "n"(W) : "memory");                              \
        asm volatile("s_barrier" ::: "memory");                                                \
        const float* Ab = &As[(it) % 3][0];                                                    \
        const unsigned short* Bb = &Bsh[(it) % 3][0];                                          \
        bf16x8 af[4], bfr[4];                                                                  \
        _Pragma("unroll") for (int i = 0; i < 4; ++i) {                                        \
            int arow = wm + i * 16 + l15;                                                      \
            int c0 = (quad * 2) ^ (arow & 7), c1 = (quad * 2 + 1) ^ (arow & 7);                \
            f32x4 lo = *(const f32x4*)(Ab + arow * 32 + c0 * 4);                               \
            f32x4 hi = *(const f32x4*)(Ab + arow * 32 + c1 * 4);                               \
            unsigned int uu[4] = {pk2(lo[0], lo[1]), pk2(lo[2], lo[3]),                        \
                                  pk2(hi[0], hi[1]), pk2(hi[2], hi[3])};                       \
            __builtin_memcpy(&af[i], uu, 16);                                                  \
            int brow = wn + i * 16 + l15;                                                      \
            bfr[i] = *(const bf16x8*)(Bb + (brow * 4 + (quad ^ (l15 & 3))) * 8);               \
        }                                                                                      \
        _Pragma("unroll") for (int mi = 0; mi < 4; ++mi)                                       \
            _Pragma("unroll") for (int ni = 0; ni < 4; ++ni)                                   \
                acc[mi][ni] = __builtin_amdgcn_mfma_f32_16x16x32_bf16(af[mi], bfr[ni],         \
                                                                      acc[mi][ni], 0, 0, 0);   \
        if ((it) + 2 < 16) ISSUE((it) + 2);                                                    \
    } while (0)

    STAGE(0, 6);  STAGE(1, 6);  STAGE(2, 6);  STAGE(3, 6);
    STAGE(4, 6);  STAGE(5, 6);  STAGE(6, 6);  STAGE(7, 6);
    STAGE(8, 6);  STAGE(9, 6);  STAGE(10, 6); STAGE(11, 6);
    STAGE(12, 6); STAGE(13, 6); STAGE(14, 6); STAGE(15, 0);
#undef STAGE
#undef ISSUE

    // epilogue: gelu(acc + b1) * W2, partial dot over this wave's 64 cols
    float pr[4][4];
#pragma unroll
    for (int mi = 0; mi < 4; ++mi)
#pragma unroll
        for (int r = 0; r < 4; ++r) pr[mi][r] = 0.f;
#pragma unroll
    for (int ni = 0; ni < 4; ++ni) {
        int n = n0 + wn + ni * 16 + l15;
        float bb = b1[t * E_N + n];
        float w2 = W2[t * E_N + n];
#pragma unroll
        for (int mi = 0; mi < 4; ++mi)
#pragma unroll
            for (int r = 0; r < 4; ++r) {
                float u = acc[mi][ni][r] + bb;
                float gg = 0.5f * u * (1.f + erff(u * 0.70710678118654752f));
                pr[mi][r] = fmaf(gg, w2, pr[mi][r]);
            }
    }
#pragma unroll
    for (int off = 1; off <= 8; off <<= 1)
#pragma unroll
        for (int mi = 0; mi < 4; ++mi)
#pragma unroll
            for (int r = 0; r < 4; ++r) pr[mi][r] += __shfl_xor(pr[mi][r], off, 64);

    // plain store: slab nt*2 + (wave&1) — each (slab, b) written by exactly one wave
    if (l15 == 0) {
        float* slab = yacc8 + (size_t)(nt * 2 + (wave & 1)) * B_N;
#pragma unroll
        for (int mi = 0; mi < 4; ++mi)
#pragma unroll
            for (int r = 0; r < 4; ++r) {
                int rl = wm + mi * 16 + quad * 4 + r;  // local sorted row
                if (m0 + rl < n_t) slab[rows_s[rl]] = pr[mi][r];
            }
    }
}

__global__ void k_final8(const float* __restrict__ yacc8, const int* __restrict__ tv,
                         const float* __restrict__ b2, float* __restrict__ out) {
    int b = blockIdx.x * blockDim.x + threadIdx.x;
    if (b < B_N) {
        float x = b2[tv[b]];
#pragma unroll
        for (int s = 0; s < 8; ++s) x += yacc8[(size_t)s * B_N + b];
        out[b] = fmaxf(x, 0.f) + log1pf(expf(-fabsf(x)));  // stable softplus
    }
}

// ================= fallback (fp32 path, proven) =================
__global__ __launch_bounds__(256) void k_prep_sb(
    const int* __restrict__ tv, int* __restrict__ offs_g,
    int* __restrict__ rank, int* __restrict__ order, float* __restrict__ yacc) {
    __shared__ int lh[4][32], wcur[4][32], offs_s[33];
    int tid = threadIdx.x, w = tid >> 6;
    if (tid < 128) lh[tid >> 5][tid & 31] = 0;
    __syncthreads();
    int tval[32];
#pragma unroll
    for (int c = 0; c < 32; ++c) tval[c] = tv[c * 256 + tid];
#pragma unroll
    for (int c = 0; c < 32; ++c) atomicAdd(&lh[w][tval[c]], 1);
    __syncthreads();
    if (tid < 32) {
        int s = lh[0][tid] + lh[1][tid] + lh[2][tid] + lh[3][tid];
        int excl = 0;
#pragma unroll
        for (int i = 0; i < 32; ++i) {
            int v = __shfl(s, i, 64);
            if (i < tid) excl += v;
        }
        offs_s[tid] = excl;
        offs_g[tid] = excl;
        if (tid == 31) { offs_s[32] = excl + s; offs_g[32] = excl + s; }
    }
    __syncthreads();
    if (tid < 128) {
        int ww = tid >> 5, t = tid & 31;
        int s = offs_s[t];
        for (int w2 = 0; w2 < ww; ++w2) s += lh[w2][t];
        wcur[ww][t] = s;
    }
    __syncthreads();
#pragma unroll
    for (int c = 0; c < 32; ++c) {
        int b = c * 256 + tid;
        int pos = atomicAdd(&wcur[w][tval[c]], 1);
        rank[b] = pos;
        order[pos] = b;
    }
    float4 z = make_float4(0.f, 0.f, 0.f, 0.f);
#pragma unroll
    for (int c = 0; c < 8; ++c) *(float4*)(yacc + (c * 256 + tid) * 4) = z;
}

__global__ __launch_bounds__(256) void fb_gemm(
    const float* __restrict__ g_exp, const float* __restrict__ W1,
    const float* __restrict__ b1, const float* __restrict__ W2,
    const int* __restrict__ offs, const int* __restrict__ order,
    float* __restrict__ yacc) {
    int t = blockIdx.z;
    int base = offs[t];
    int n_t = offs[t + 1] - base;
    int m0 = blockIdx.y * 64;
    if (m0 >= n_t) return;
    int n0 = blockIdx.x * 128;

    __shared__ float As[32][68];
    __shared__ float Bs[32][128];
    __shared__ int sidx[64];

    int tid = threadIdx.x;
    if (tid < 64) {
        int m = m0 + tid;
        sidx[tid] = (m < n_t) ? order[base + m] : -1;
    }
    __syncthreads();

    int ty = tid >> 4, tx = tid & 15;
    float acc[4][8];
#pragma unroll
    for (int r = 0; r < 4; ++r)
#pragma unroll
        for (int c = 0; c < 8; ++c) acc[r][c] = 0.f;

    for (int k0 = 0; k0 < E_N; k0 += 32) {
#pragma unroll
        for (int p = 0; p < 2; ++p) {
            int idx = tid + 256 * p;
            int row = idx >> 3, kcq = idx & 7;
            int s = sidx[row];
            float4 v = make_float4(0.f, 0.f, 0.f, 0.f);
            if (s >= 0) v = *(const float4*)(g_exp + (size_t)s * E_N + k0 + kcq * 4);
            As[kcq * 4 + 0][row] = v.x;
            As[kcq * 4 + 1][row] = v.y;
            As[kcq * 4 + 2][row] = v.z;
            As[kcq * 4 + 3][row] = v.w;
        }
#pragma unroll
        for (int p = 0; p < 4; ++p) {
            int idx = tid + 256 * p;
            int kr = idx >> 5, c4 = idx & 31;
            *(float4*)(&Bs[kr][c4 * 4]) =
                *(const float4*)(W1 + ((size_t)t * E_N + (k0 + kr)) * E_N + n0 + c4 * 4);
        }
        __syncthreads();
#pragma unroll
        for (int e = 0; e < 32; ++e) {
            float4 a = *(const float4*)(&As[e][ty * 4]);
            float4 bA = *(const float4*)(&Bs[e][tx * 4]);
            float4 bB = *(const float4*)(&Bs[e][tx * 4 + 64]);
            float av[4] = {a.x, a.y, a.z, a.w};
            float bv[8] = {bA.x, bA.y, bA.z, bA.w, bB.x, bB.y, bB.z, bB.w};
#pragma unroll
            for (int r = 0; r < 4; ++r)
#pragma unroll
                for (int c = 0; c < 8; ++c) acc[r][c] = fmaf(av[r], bv[c], acc[r][c]);
        }
        __syncthreads();
    }

    float pr[4] = {0.f, 0.f, 0.f, 0.f};
#pragma unroll
    for (int c = 0; c < 8; ++c) {
        int n = n0 + tx * 4 + ((c >= 4) ? 64 : 0) + (c & 3);
        float bb = b1[t * E_N + n];
        float w2 = W2[t * E_N + n];
#pragma unroll
        for (int r = 0; r < 4; ++r) {
            float u = acc[r][c] + bb;
            float g = 0.5f * u * (1.f + erff(u * 0.70710678118654752f));
            pr[r] = fmaf(g, w2, pr[r]);
        }
    }
#pragma unroll
    for (int off = 8; off >= 1; off >>= 1)
#pragma unroll
        for (int r = 0; r < 4; ++r) pr[r] += __shfl_xor(pr[r], off, 64);

    if (tx == 0) {
#pragma unroll
        for (int r = 0; r < 4; ++r) {
            int m = m0 + ty * 4 + r;
            if (m < n_t) atomicAdd(&yacc[sidx[ty * 4 + r]], pr[r]);
        }
    }
}

__global__ void fb_final(const float* __restrict__ yacc, const int* __restrict__ tv,
                         const float* __restrict__ b2, float* __restrict__ out) {
    int b = blockIdx.x * blockDim.x + threadIdx.x;
    if (b < B_N) {
        float x = yacc[b] + b2[tv[b]];
        out[b] = fmaxf(x, 0.f) + log1pf(expf(-fabsf(x)));
    }
}

extern "C" void kernel_launch(void* const* d_in, const int* in_sizes, int n_in,
                              void* d_out, int out_size, void* d_ws, size_t ws_size,
                              hipStream_t stream) {
    const float* g_exp = (const float*)d_in[0];
    const int*   tv    = (const int*)d_in[1];
    const float* W1    = (const float*)d_in[2];
    const float* b1    = (const float*)d_in[3];
    const float* W2    = (const float*)d_in[4];
    const float* b2    = (const float*)d_in[5];
    float* out = (float*)d_out;

    char* ws = (char*)d_ws;

    if (ws_size >= (size_t)WS_REQ) {
        float* yacc8 = (float*)(ws + WS_YACC8);
        unsigned short* W1T = (unsigned short*)(ws + WS_W1T);
        k_pre<<<2048, 256, 0, stream>>>(W1, W1T);
        k_gemm_mfma<<<512, 256, 0, stream>>>(g_exp, W1T, tv, b1, W2, yacc8);
        k_final8<<<32, 256, 0, stream>>>(yacc8, tv, b2, out);
    } else {
        int* offs   = (int*)(ws + WS_OFFS);
        int* rank   = (int*)(ws + WS_RANK);
        int* order  = (int*)(ws + WS_ORDER);
        float* yacc = (float*)(ws + WS_YACC);
        k_prep_sb<<<1, 256, 0, stream>>>(tv, offs, rank, order, yacc);
        fb_gemm<<<dim3(4, 8, 32), 256, 0, stream>>>(g_exp, W1, b1, W2, offs, order, yacc);
        fb_final<<<32, 256, 0, stream>>>(yacc, tv, b2, out);
    }
}